// Round 4
// baseline (271.972 us; speedup 1.0000x reference)
//
#include <hip/hip_runtime.h>
#include <math.h>

#define C_ 256
#define CR_ 16
#define B_ 16
#define HW_ (128*128)

#define NBLK 256        // 1 block per CU -- cooperative co-residency trivially satisfied
#define TPB  512        // 8 waves/block
#define CPB  16         // channels per block   (4096 / 256)
#define CPW  2          // channels per wave    (8 waves/block)
#define CD   16         // f32x4 chunks cached in regs per channel (of 64) -> 128 VGPR

typedef float f32x4 __attribute__((ext_vector_type(4)));

__device__ __forceinline__ float agent_load(const float* p) {
    return __hip_atomic_load(p, __ATOMIC_RELAXED, __HIP_MEMORY_SCOPE_AGENT);
}
__device__ __forceinline__ void agent_store(float* p, float v) {
    __hip_atomic_store(p, v, __ATOMIC_RELAXED, __HIP_MEMORY_SCOPE_AGENT);
}

// Single-use grid barrier. cnt/gen must be zeroed before the launch (memsetAsync).
__device__ __forceinline__ void grid_barrier(unsigned* cnt, unsigned* gen) {
    __syncthreads();
    if (threadIdx.x == 0) {
        unsigned old = __hip_atomic_fetch_add(cnt, 1u, __ATOMIC_ACQ_REL,
                                              __HIP_MEMORY_SCOPE_AGENT);
        if (old == (unsigned)(NBLK - 1)) {
            __hip_atomic_store(gen, 1u, __ATOMIC_RELEASE, __HIP_MEMORY_SCOPE_AGENT);
        } else {
            while (__hip_atomic_load(gen, __ATOMIC_ACQUIRE,
                                     __HIP_MEMORY_SCOPE_AGENT) == 0u) {
                __builtin_amdgcn_s_sleep(2);
            }
        }
    }
    __syncthreads();
}

__global__ __launch_bounds__(TPB, 2) void fused_kernel(
    const float* __restrict__ x,
    const float* __restrict__ w1s, const float* __restrict__ b1s,
    const float* __restrict__ w2s, const float* __restrict__ b2s,
    const float* __restrict__ w1m, const float* __restrict__ b1m,
    const float* __restrict__ w2m, const float* __restrict__ b2m,
    const float* __restrict__ wb,  const float* __restrict__ bb,
    const float* __restrict__ w1f, const float* __restrict__ b1f,
    const float* __restrict__ w2f, const float* __restrict__ b2f,
    float* __restrict__ out,
    float* mean_ws, float* std_ws, float* mask_ws, unsigned* bar)
{
    const int bid  = blockIdx.x;
    const int t    = threadIdx.x;
    const int w    = t >> 6;
    const int lane = t & 63;

    __shared__ float ds[C_], dm[C_];
    __shared__ float h1s[CR_], h1m[CR_];
    __shared__ float fused[2 * C_];
    __shared__ float fb[C_];
    __shared__ float h1f[CR_];

    f32x4 cache[CPW][CD];

    // ---------------- phase 1: per-channel mean/std (wave per 2 channels) ---
    #pragma unroll
    for (int cc = 0; cc < CPW; ++cc) {
        const int gch = bid * CPB + w * CPW + cc;        // global b*C + c
        const f32x4* xp = (const f32x4*)(x + (size_t)gch * HW_);
        float s = 0.f, ss = 0.f;
        #pragma unroll
        for (int i = 0; i < CD; ++i) {                   // reg-cached portion
            f32x4 v = xp[lane + i * 64];
            cache[cc][i] = v;
            s  += v.x + v.y + v.z + v.w;
            ss += v.x * v.x + v.y * v.y + v.z * v.z + v.w * v.w;
        }
        #pragma unroll 4
        for (int i = CD; i < 64; ++i) {                  // streamed portion
            f32x4 v = xp[lane + i * 64];
            s  += v.x + v.y + v.z + v.w;
            ss += v.x * v.x + v.y * v.y + v.z * v.z + v.w * v.w;
        }
        #pragma unroll
        for (int m = 1; m < 64; m <<= 1) {
            s  += __shfl_xor(s, m, 64);
            ss += __shfl_xor(ss, m, 64);
        }
        if (lane == 0) {
            float mean = s * (1.0f / HW_);
            float var  = ss * (1.0f / HW_) - mean * mean;
            agent_store(&mean_ws[gch], mean);
            agent_store(&std_ws[gch], sqrtf(fmaxf(var, 0.f)));
        }
    }

    grid_barrier(&bar[0], &bar[1]);

    // ---------------- phase 2: MLP chain on blocks 0..15 --------------------
    if (bid < B_) {
        const int b = bid;
        if (t < C_) {
            ds[t] = agent_load(&std_ws[b * C_ + t]);
            dm[t] = agent_load(&mean_ws[b * C_ + t]);
        }
        __syncthreads();

        if (t < 32) {
            const int r = t & 15;
            const bool is_std = (t < 16);
            const float* wgt = is_std ? w1s : w1m;
            const float* src = is_std ? ds : dm;
            float acc = is_std ? b1s[r] : b1m[r];
            for (int c = 0; c < C_; ++c) acc += src[c] * wgt[r * C_ + c];
            acc = fmaxf(acc, 0.f);
            if (is_std) h1s[r] = acc; else h1m[r] = acc;
        }
        __syncthreads();

        if (t < C_) {
            float accs = b2s[t], accm = b2m[t];
            #pragma unroll
            for (int r = 0; r < CR_; ++r) {
                accs += h1s[r] * w2s[t * CR_ + r];
                accm += h1m[r] * w2m[t * CR_ + r];
            }
            fused[t]      = accs;
            fused[C_ + t] = accm;
        }
        __syncthreads();

        if (t < C_) {
            float acc = bb[t];
            const f32x4* wr = (const f32x4*)(wb + (size_t)t * 2 * C_);
            #pragma unroll 4
            for (int j = 0; j < 2 * C_ / 4; ++j) {
                f32x4 w4 = wr[j];
                acc += fused[4 * j]     * w4.x + fused[4 * j + 1] * w4.y
                     + fused[4 * j + 2] * w4.z + fused[4 * j + 3] * w4.w;
            }
            fb[t] = fmaxf(acc, 0.f);
        }
        __syncthreads();

        if (t < CR_) {
            float acc = b1f[t];
            for (int c = 0; c < C_; ++c) acc += fb[c] * w1f[t * C_ + c];
            h1f[t] = fmaxf(acc, 0.f);
        }
        __syncthreads();

        if (t < C_) {
            float acc = b2f[t];
            #pragma unroll
            for (int r = 0; r < CR_; ++r) acc += h1f[r] * w2f[t * CR_ + r];
            agent_store(&mask_ws[b * C_ + t], 1.0f / (1.0f + expf(-acc)));
        }
    }

    grid_barrier(&bar[2], &bar[3]);

    // ---------------- phase 3: scale (reg-cached portion + streamed) --------
    #pragma unroll
    for (int cc = 0; cc < CPW; ++cc) {
        const int gch = bid * CPB + w * CPW + cc;
        const float m = agent_load(&mask_ws[gch]);
        const f32x4* xp = (const f32x4*)(x + (size_t)gch * HW_);
        f32x4* op = (f32x4*)(out + (size_t)gch * HW_);
        #pragma unroll
        for (int i = 0; i < CD; ++i) {
            f32x4 v = cache[cc][i];
            v.x *= m; v.y *= m; v.z *= m; v.w *= m;
            __builtin_nontemporal_store(v, op + lane + i * 64);
        }
        #pragma unroll 4
        for (int i = CD; i < 64; ++i) {
            f32x4 v = xp[lane + i * 64];
            v.x *= m; v.y *= m; v.z *= m; v.w *= m;
            __builtin_nontemporal_store(v, op + lane + i * 64);
        }
    }
}

extern "C" void kernel_launch(void* const* d_in, const int* in_sizes, int n_in,
                              void* d_out, int out_size, void* d_ws, size_t ws_size,
                              hipStream_t stream) {
    const float* x   = (const float*)d_in[0];
    const float* w1s = (const float*)d_in[1];
    const float* b1s = (const float*)d_in[2];
    const float* w2s = (const float*)d_in[3];
    const float* b2s = (const float*)d_in[4];
    const float* w1m = (const float*)d_in[5];
    const float* b1m = (const float*)d_in[6];
    const float* w2m = (const float*)d_in[7];
    const float* b2m = (const float*)d_in[8];
    const float* wb  = (const float*)d_in[9];
    const float* bb  = (const float*)d_in[10];
    const float* w1f = (const float*)d_in[11];
    const float* b1f = (const float*)d_in[12];
    const float* w2f = (const float*)d_in[13];
    const float* b2f = (const float*)d_in[14];
    float* out = (float*)d_out;

    float*    mean_ws = (float*)d_ws;              // [0,   4096) floats
    float*    std_ws  = mean_ws + B_ * C_;         // [4096, 8192)
    float*    mask_ws = std_ws + B_ * C_;          // [8192,12288)
    unsigned* bar     = (unsigned*)(mask_ws + B_ * C_);  // 4 u32 barrier slots

    // zero the barrier slots every call (captured into the graph)
    hipMemsetAsync((void*)bar, 0, 4 * sizeof(unsigned), stream);

    void* args[] = {
        (void*)&x,
        (void*)&w1s, (void*)&b1s, (void*)&w2s, (void*)&b2s,
        (void*)&w1m, (void*)&b1m, (void*)&w2m, (void*)&b2m,
        (void*)&wb,  (void*)&bb,
        (void*)&w1f, (void*)&b1f, (void*)&w2f, (void*)&b2f,
        (void*)&out,
        (void*)&mean_ws, (void*)&std_ws, (void*)&mask_ws, (void*)&bar,
    };
    hipError_t err = hipLaunchCooperativeKernel((const void*)fused_kernel,
                                                dim3(NBLK), dim3(TPB), args, 0, stream);
    if (err != hipSuccess) {
        // fallback: plain launch. 256 blocks at 1 block/CU on a 256-CU chip are
        // co-resident in practice, so the barrier still completes.
        fused_kernel<<<dim3(NBLK), dim3(TPB), 0, stream>>>(
            x, w1s, b1s, w2s, b2s, w1m, b1m, w2m, b2m, wb, bb,
            w1f, b1f, w2f, b2f, out, mean_ws, std_ws, mask_ws, bar);
    }
}

// Round 5
// 266.037 us; speedup vs baseline: 1.0223x; 1.0223x over previous
//
#include <hip/hip_runtime.h>
#include <math.h>

#define C_ 256
#define CR_ 16
#define B_ 16
#define HW_ (128*128)

#define NBLK 512        // 2 blocks/CU on 256 CUs
#define TPB  1024       // 16 waves/block -> 32 waves/CU (full occupancy)
#define CPB  8          // channels per block (4096 / 512); 2 waves per channel

typedef float f32x4 __attribute__((ext_vector_type(4)));

__device__ __forceinline__ float agent_load(const float* p) {
    return __hip_atomic_load(p, __ATOMIC_RELAXED, __HIP_MEMORY_SCOPE_AGENT);
}
__device__ __forceinline__ void agent_store(float* p, float v) {
    __hip_atomic_store(p, v, __ATOMIC_RELAXED, __HIP_MEMORY_SCOPE_AGENT);
}

// Single-use grid barrier; cnt/gen zeroed by memsetAsync before each launch.
__device__ __forceinline__ void grid_barrier(unsigned* cnt, unsigned* gen) {
    __syncthreads();
    if (threadIdx.x == 0) {
        unsigned old = __hip_atomic_fetch_add(cnt, 1u, __ATOMIC_ACQ_REL,
                                              __HIP_MEMORY_SCOPE_AGENT);
        if (old == (unsigned)(NBLK - 1)) {
            __hip_atomic_store(gen, 1u, __ATOMIC_RELEASE, __HIP_MEMORY_SCOPE_AGENT);
        } else {
            while (__hip_atomic_load(gen, __ATOMIC_ACQUIRE,
                                     __HIP_MEMORY_SCOPE_AGENT) == 0u) {
                __builtin_amdgcn_s_sleep(2);
            }
        }
    }
    __syncthreads();
}

__global__ __launch_bounds__(TPB, 2) void asca_fused(
    const float* __restrict__ x,
    const float* __restrict__ w1s, const float* __restrict__ b1s,
    const float* __restrict__ w2s, const float* __restrict__ b2s,
    const float* __restrict__ w1m, const float* __restrict__ b1m,
    const float* __restrict__ w2m, const float* __restrict__ b2m,
    const float* __restrict__ wb,  const float* __restrict__ bb,
    const float* __restrict__ w1f, const float* __restrict__ b1f,
    const float* __restrict__ w2f, const float* __restrict__ b2f,
    float* __restrict__ out,
    float* mean_ws, float* std_ws, unsigned* bar)
{
    const int bid  = blockIdx.x;
    const int t    = threadIdx.x;
    const int w    = t >> 6;          // wave 0..15
    const int lane = t & 63;
    const int half = w & 1;           // which half of the channel this wave does
    const int cib  = w >> 1;          // channel-in-block 0..7
    const int gch  = bid * CPB + cib; // global b*C + c

    __shared__ float sm[16][2];
    __shared__ float ds[C_], dm[C_];
    __shared__ float h1s[CR_], h1m[CR_];
    __shared__ float fsd[2 * C_];
    __shared__ float fb[C_];
    __shared__ float h1f[CR_];
    __shared__ float msk[C_];

    const f32x4* xp = (const f32x4*)(x + (size_t)gch * HW_);

    // ---------------- phase 1: per-channel sum/sumsq (2 waves per channel) --
    {
        f32x4 s4 = {0.f, 0.f, 0.f, 0.f}, q4 = {0.f, 0.f, 0.f, 0.f};
        const int i0 = half * 32;
        #pragma unroll 8
        for (int i = i0; i < i0 + 32; ++i) {
            f32x4 v = xp[lane + i * 64];
            s4 += v;
            q4 += v * v;
        }
        float s  = s4.x + s4.y + s4.z + s4.w;
        float ss = q4.x + q4.y + q4.z + q4.w;
        #pragma unroll
        for (int m = 1; m < 64; m <<= 1) {
            s  += __shfl_xor(s, m, 64);
            ss += __shfl_xor(ss, m, 64);
        }
        if (lane == 0) { sm[w][0] = s; sm[w][1] = ss; }
    }
    __syncthreads();
    if (t < CPB) {                    // combine the two half-channel waves
        float s  = sm[2 * t][0] + sm[2 * t + 1][0];
        float ss = sm[2 * t][1] + sm[2 * t + 1][1];
        const int g = bid * CPB + t;
        float mean = s * (1.0f / HW_);
        float var  = ss * (1.0f / HW_) - mean * mean;
        agent_store(&mean_ws[g], mean);
        agent_store(&std_ws[g], sqrtf(fmaxf(var, 0.f)));
    }

    grid_barrier(&bar[0], &bar[1]);

    // ------- phase 2: MLP, computed redundantly per block for its batch -----
    const int b = bid / (C_ / CPB);   // 32 blocks per batch row
    if (t < C_) {
        ds[t] = agent_load(&std_ws[b * C_ + t]);
        dm[t] = agent_load(&mean_ws[b * C_ + t]);
    }
    __syncthreads();

    if (t < 32) {
        const int r = t & 15;
        const bool is_std = (t < 16);
        const float* wgt = is_std ? w1s : w1m;
        const float* src = is_std ? ds : dm;
        float acc = is_std ? b1s[r] : b1m[r];
        for (int c = 0; c < C_; ++c) acc += src[c] * wgt[r * C_ + c];
        acc = fmaxf(acc, 0.f);
        if (is_std) h1s[r] = acc; else h1m[r] = acc;
    }
    __syncthreads();

    if (t < C_) {
        float accs = b2s[t], accm = b2m[t];
        #pragma unroll
        for (int r = 0; r < CR_; ++r) {
            accs += h1s[r] * w2s[t * CR_ + r];
            accm += h1m[r] * w2m[t * CR_ + r];
        }
        fsd[t]      = accs;
        fsd[C_ + t] = accm;
    }
    __syncthreads();

    if (t < C_) {
        float acc = bb[t];
        const f32x4* wr = (const f32x4*)(wb + (size_t)t * 2 * C_);
        #pragma unroll 4
        for (int j = 0; j < 2 * C_ / 4; ++j) {
            f32x4 w4 = wr[j];
            acc += fsd[4 * j]     * w4.x + fsd[4 * j + 1] * w4.y
                 + fsd[4 * j + 2] * w4.z + fsd[4 * j + 3] * w4.w;
        }
        fb[t] = fmaxf(acc, 0.f);
    }
    __syncthreads();

    if (t < CR_) {
        float acc = b1f[t];
        for (int c = 0; c < C_; ++c) acc += fb[c] * w1f[t * C_ + c];
        h1f[t] = fmaxf(acc, 0.f);
    }
    __syncthreads();

    if (t < C_) {
        float acc = b2f[t];
        #pragma unroll
        for (int r = 0; r < CR_; ++r) acc += h1f[r] * w2f[t * CR_ + r];
        msk[t] = 1.0f / (1.0f + expf(-acc));
    }
    __syncthreads();

    // ---------------- phase 3: scale + nt store -----------------------------
    {
        const float m = msk[gch & (C_ - 1)];
        f32x4* op = (f32x4*)(out + (size_t)gch * HW_);
        const int i0 = half * 32;
        #pragma unroll 8
        for (int i = i0; i < i0 + 32; ++i) {
            f32x4 v = xp[lane + i * 64];
            v *= m;
            __builtin_nontemporal_store(v, op + lane + i * 64);
        }
    }
}

extern "C" void kernel_launch(void* const* d_in, const int* in_sizes, int n_in,
                              void* d_out, int out_size, void* d_ws, size_t ws_size,
                              hipStream_t stream) {
    const float* x   = (const float*)d_in[0];
    const float* w1s = (const float*)d_in[1];
    const float* b1s = (const float*)d_in[2];
    const float* w2s = (const float*)d_in[3];
    const float* b2s = (const float*)d_in[4];
    const float* w1m = (const float*)d_in[5];
    const float* b1m = (const float*)d_in[6];
    const float* w2m = (const float*)d_in[7];
    const float* b2m = (const float*)d_in[8];
    const float* wb  = (const float*)d_in[9];
    const float* bb  = (const float*)d_in[10];
    const float* w1f = (const float*)d_in[11];
    const float* b1f = (const float*)d_in[12];
    const float* w2f = (const float*)d_in[13];
    const float* b2f = (const float*)d_in[14];
    float* out = (float*)d_out;

    float*    mean_ws = (float*)d_ws;                    // B*C floats
    float*    std_ws  = mean_ws + B_ * C_;               // B*C floats
    unsigned* bar     = (unsigned*)(std_ws + B_ * C_);   // 2 u32 barrier slots

    hipMemsetAsync((void*)bar, 0, 2 * sizeof(unsigned), stream);

    void* args[] = {
        (void*)&x,
        (void*)&w1s, (void*)&b1s, (void*)&w2s, (void*)&b2s,
        (void*)&w1m, (void*)&b1m, (void*)&w2m, (void*)&b2m,
        (void*)&wb,  (void*)&bb,
        (void*)&w1f, (void*)&b1f, (void*)&w2f, (void*)&b2f,
        (void*)&out,
        (void*)&mean_ws, (void*)&std_ws, (void*)&bar,
    };
    hipError_t err = hipLaunchCooperativeKernel((const void*)asca_fused,
                                                dim3(NBLK), dim3(TPB), args, 0, stream);
    if (err != hipSuccess) {
        // fallback: plain launch (512 blocks at 2/CU are co-resident in practice)
        asca_fused<<<dim3(NBLK), dim3(TPB), 0, stream>>>(
            x, w1s, b1s, w2s, b2s, w1m, b1m, w2m, b2m, wb, bb,
            w1f, b1f, w2f, b2f, out, mean_ws, std_ws, bar);
    }
}

// Round 6
// 164.418 us; speedup vs baseline: 1.6542x; 1.6181x over previous
//
#include <hip/hip_runtime.h>
#include <math.h>

#define C_ 256
#define CR_ 16
#define B_ 16
#define HW_ (128*128)

typedef float f32x4 __attribute__((ext_vector_type(4)));

__global__ __launch_bounds__(256) void stats_kernel(const float* __restrict__ x,
                                                    float* __restrict__ mean_out,
                                                    float* __restrict__ std_out) {
    const int ch = blockIdx.x;                    // b*C + c
    const f32x4* xp = (const f32x4*)(x + (size_t)ch * HW_);
    const int t = threadIdx.x;
    float s = 0.f, ss = 0.f;
    #pragma unroll
    for (int i = 0; i < HW_ / 4 / 256; ++i) {     // 16 float4 per thread
        f32x4 v = xp[t + i * 256];
        s  += v.x + v.y + v.z + v.w;
        ss += v.x * v.x + v.y * v.y + v.z * v.z + v.w * v.w;
    }
    // wave64 reduce
    #pragma unroll
    for (int off = 32; off > 0; off >>= 1) {
        s  += __shfl_down(s, off, 64);
        ss += __shfl_down(ss, off, 64);
    }
    __shared__ float ls[4], lss[4];
    const int wid = t >> 6;
    if ((t & 63) == 0) { ls[wid] = s; lss[wid] = ss; }
    __syncthreads();
    if (t == 0) {
        float S  = ls[0] + ls[1] + ls[2] + ls[3];
        float SS = lss[0] + lss[1] + lss[2] + lss[3];
        float m = S * (1.0f / HW_);
        float v = SS * (1.0f / HW_) - m * m;
        mean_out[ch] = m;
        std_out[ch]  = sqrtf(fmaxf(v, 0.f));
    }
}

__global__ __launch_bounds__(256) void mlp_kernel(
    const float* __restrict__ mean_d, const float* __restrict__ std_d,
    const float* __restrict__ w1s, const float* __restrict__ b1s,
    const float* __restrict__ w2s, const float* __restrict__ b2s,
    const float* __restrict__ w1m, const float* __restrict__ b1m,
    const float* __restrict__ w2m, const float* __restrict__ b2m,
    const float* __restrict__ wb,  const float* __restrict__ bb,
    const float* __restrict__ w1f, const float* __restrict__ b1f,
    const float* __restrict__ w2f, const float* __restrict__ b2f,
    float* __restrict__ mask_out)
{
    const int b = blockIdx.x;
    const int t = threadIdx.x;
    __shared__ float ds[C_], dm[C_];
    __shared__ float h1s[CR_], h1m[CR_];
    __shared__ float fused[2 * C_];
    __shared__ float fb[C_];
    __shared__ float h1f[CR_];

    ds[t] = std_d[b * C_ + t];
    dm[t] = mean_d[b * C_ + t];
    __syncthreads();

    // SE first layers: threads 0..15 -> std branch, 16..31 -> mean branch
    if (t < 32) {
        const int r = t & 15;
        const bool is_std = (t < 16);
        const float* w   = is_std ? w1s : w1m;
        const float* src = is_std ? ds : dm;
        float acc = is_std ? b1s[r] : b1m[r];
        for (int c = 0; c < C_; ++c) acc += src[c] * w[r * C_ + c];
        acc = fmaxf(acc, 0.f);
        if (is_std) h1s[r] = acc; else h1m[r] = acc;
    }
    __syncthreads();

    // SE second layers: thread t -> fused[t] (std), fused[C+t] (mean)
    {
        float accs = b2s[t], accm = b2m[t];
        #pragma unroll
        for (int r = 0; r < CR_; ++r) {
            accs += h1s[r] * w2s[t * CR_ + r];
            accm += h1m[r] * w2m[t * CR_ + r];
        }
        fused[t]      = accs;
        fused[C_ + t] = accm;
    }
    __syncthreads();

    // bottleneck: fb[t] = relu(dot(fused, wb[t,:]) + bb[t])
    {
        float acc = bb[t];
        const f32x4* wr = (const f32x4*)(wb + (size_t)t * 2 * C_);
        #pragma unroll 4
        for (int j = 0; j < 2 * C_ / 4; ++j) {
            f32x4 w4 = wr[j];
            acc += fused[4 * j]     * w4.x + fused[4 * j + 1] * w4.y
                 + fused[4 * j + 2] * w4.z + fused[4 * j + 3] * w4.w;
        }
        fb[t] = fmaxf(acc, 0.f);
    }
    __syncthreads();

    // final SE layer 1
    if (t < 16) {
        float acc = b1f[t];
        for (int c = 0; c < C_; ++c) acc += fb[c] * w1f[t * C_ + c];
        h1f[t] = fmaxf(acc, 0.f);
    }
    __syncthreads();

    // final SE layer 2 + sigmoid
    {
        float acc = b2f[t];
        #pragma unroll
        for (int r = 0; r < CR_; ++r) acc += h1f[r] * w2f[t * CR_ + r];
        mask_out[b * C_ + t] = 1.0f / (1.0f + expf(-acc));
    }
}

// 2048 blocks x 256 threads, fixed 32 trips, unroll 8.
// nt-load x (last use, don't thrash L3), nt-store out (no reuse).
__global__ __launch_bounds__(256) void scale_kernel(const float* __restrict__ x,
                                                    const float* __restrict__ mask,
                                                    float* __restrict__ out) {
    const unsigned g = blockIdx.x * 256u + threadIdx.x;   // 0 .. 524287
    const f32x4* xp = (const f32x4*)x;
    f32x4* op = (f32x4*)out;
    #pragma unroll 8
    for (int k = 0; k < 32; ++k) {
        const size_t i = (size_t)g + (size_t)k * (2048u * 256u);
        const float m = mask[i >> 12];                    // wave-uniform
        f32x4 v = __builtin_nontemporal_load(xp + i);
        v.x *= m; v.y *= m; v.z *= m; v.w *= m;
        __builtin_nontemporal_store(v, op + i);
    }
}

extern "C" void kernel_launch(void* const* d_in, const int* in_sizes, int n_in,
                              void* d_out, int out_size, void* d_ws, size_t ws_size,
                              hipStream_t stream) {
    const float* x   = (const float*)d_in[0];
    const float* w1s = (const float*)d_in[1];
    const float* b1s = (const float*)d_in[2];
    const float* w2s = (const float*)d_in[3];
    const float* b2s = (const float*)d_in[4];
    const float* w1m = (const float*)d_in[5];
    const float* b1m = (const float*)d_in[6];
    const float* w2m = (const float*)d_in[7];
    const float* b2m = (const float*)d_in[8];
    const float* wb  = (const float*)d_in[9];
    const float* bb  = (const float*)d_in[10];
    const float* w1f = (const float*)d_in[11];
    const float* b1f = (const float*)d_in[12];
    const float* w2f = (const float*)d_in[13];
    const float* b2f = (const float*)d_in[14];
    float* out = (float*)d_out;

    float* mean_ws = (float*)d_ws;                 // B*C floats
    float* std_ws  = mean_ws + B_ * C_;            // B*C floats
    float* mask_ws = std_ws + B_ * C_;             // B*C floats

    stats_kernel<<<B_ * C_, 256, 0, stream>>>(x, mean_ws, std_ws);
    mlp_kernel<<<B_, 256, 0, stream>>>(mean_ws, std_ws,
                                       w1s, b1s, w2s, b2s,
                                       w1m, b1m, w2m, b2m,
                                       wb, bb, w1f, b1f, w2f, b2f,
                                       mask_ws);
    scale_kernel<<<2048, 256, 0, stream>>>(x, mask_ws, out);
}